// Round 5
// baseline (71.217 us; speedup 1.0000x reference)
//
#include <hip/hip_runtime.h>
#include <math.h>
#include <stdint.h>

#define D_MODEL 128
#define EDGE_DIM 9
#define HIDDEN 256
#define BATCH 2
#define NN 512

#define TI 4     // i-tile in kernel 2
#define TJ 64    // j-tile in kernel 2

typedef _Float16 h2v   __attribute__((ext_vector_type(2)));
typedef _Float16 f16x8 __attribute__((ext_vector_type(8)));
typedef float    f32x4 __attribute__((ext_vector_type(4)));

struct H8 { h2v v[4]; };   // 16B = one MFMA A/B fragment

__device__ __forceinline__ uint32_t h2u(h2v v) { return __builtin_bit_cast(uint32_t, v); }
__device__ __forceinline__ h2v u2h(uint32_t u) { return __builtin_bit_cast(h2v, u); }
__device__ __forceinline__ h2v pkrtz(float a, float b) {
    return __builtin_bit_cast(h2v, __builtin_amdgcn_cvt_pkrtz(a, b));
}
__device__ __forceinline__ h2v relu2(h2v v) {
    h2v z = {(_Float16)0.0f, (_Float16)0.0f};
    return __builtin_elementwise_max(v, z);
}
__device__ __forceinline__ float sigmoidf_(float x) { return 1.f / (1.f + expf(-x)); }

// ---------------------------------------------------------------------------
// Kernel 1: pi = f16(z@We_i + be1), pj = f16(z@We_j), organ head f32.
// 256 blocks x 512 threads. Block = 4 rows x 256 h. Wave w: row w>>1,
// h-half w&1; lane owns 2 h (float2 weight loads). Organ completes in-block.
// ---------------------------------------------------------------------------
__global__ __launch_bounds__(512) void node_proj_kernel(
    const float* __restrict__ z,      // (B*N, 128)
    const float* __restrict__ Wo1,    // (128,256)
    const float* __restrict__ bo1,    // (256)
    const float* __restrict__ Wo2,    // (256,1)
    const float* __restrict__ bo2,    // (1)
    const float* __restrict__ We_i,   // (128,256)
    const float* __restrict__ We_j,   // (128,256)
    const float* __restrict__ be1,    // (256)
    float* __restrict__ organ_out,    // (B*N)
    uint32_t* __restrict__ pi_h,      // (B*N,128) half2, includes +be1
    uint32_t* __restrict__ pj_h)      // (B*N,128) half2
{
    __shared__ float z_s[4][D_MODEL];
    __shared__ float red_s[4][2];

    const int t  = threadIdx.x;
    const int r0 = blockIdx.x * 4;

    z_s[t >> 7][t & 127] = z[r0 * D_MODEL + t];
    __syncthreads();

    const int wave  = t >> 6;
    const int lane  = t & 63;
    const int row_l = wave >> 1;          // 0..3
    const int hh    = wave & 1;           // h-half
    const int hp    = hh * 64 + lane;     // float2 index; h = 2*hp, 2*hp+1

    float2 accO = ((const float2*)bo1)[hp];
    float2 accI = ((const float2*)be1)[hp];
    float2 accJ = {0.f, 0.f};

    const float* zr = &z_s[row_l][0];

#pragma unroll 8
    for (int d = 0; d < D_MODEL; ++d) {
        const float2 w1 = ((const float2*)Wo1 )[d * 128 + hp];
        const float2 wi = ((const float2*)We_i)[d * 128 + hp];
        const float2 wj = ((const float2*)We_j)[d * 128 + hp];
        const float zv = zr[d];
        accO.x = fmaf(zv, w1.x, accO.x); accO.y = fmaf(zv, w1.y, accO.y);
        accI.x = fmaf(zv, wi.x, accI.x); accI.y = fmaf(zv, wi.y, accI.y);
        accJ.x = fmaf(zv, wj.x, accJ.x); accJ.y = fmaf(zv, wj.y, accJ.y);
    }

    // organ partial over this half's 128 h
    const float2 wo2 = ((const float2*)Wo2)[hp];
    float v = fmaf(fmaxf(accO.x, 0.f), wo2.x, fmaxf(accO.y, 0.f) * wo2.y);
#pragma unroll
    for (int s = 1; s <= 32; s <<= 1) v += __shfl_xor(v, s, 64);
    if (lane == 0) red_s[row_l][hh] = v;

    // pi/pj packed f16
    const size_t row = (size_t)(r0 + row_l);
    pi_h[row * 128 + hp] = h2u(pkrtz(accI.x, accI.y));
    pj_h[row * 128 + hp] = h2u(pkrtz(accJ.x, accJ.y));

    __syncthreads();
    if (t < 4) {
        organ_out[r0 + t] = sigmoidf_(red_s[t][0] + red_s[t][1] + bo2[0]);
    }
}

// ---------------------------------------------------------------------------
// Kernel 2: fused edge head with MFMA h-reduction.
// grid 1024 x 512 thr (8 waves). Wave w covers jl in [w*8, w*8+8) x TI=4 i
// = 32 pairs = 2 MFMA groups of 16 (4i x 4j). Lane: pair r=lane&15
// (i = i0 + (r>>2), j = j0 + w*8 + g*4 + (r&3)), h-chunk c=lane>>4.
// K-loop t8=0..7 over 32-h windows: lane computes v = relu(pe+pi+pj) for its
// 8 h (A-frag layout: row=lane&15, k=(lane>>4)*8+e), B = We2 slice broadcast
// to all 16 cols, C(f32x4, init be2) accumulates. No cross-lane reduce, no
// main-loop barriers. Epilogue: lanes r==0 hold rows 4c..4c+3 of col 0 ->
// sigmoid*mask, float4 store (j-consecutive).
// ---------------------------------------------------------------------------
__global__ __launch_bounds__(512, 4) void edge_kernel(
    const float* __restrict__ E,      // (N,N,9)
    const int*   __restrict__ mask,   // (N,N)
    const float* __restrict__ We_e,   // (9,256)
    const float* __restrict__ We2,    // (256,1)
    const float* __restrict__ be2,    // (1)
    const uint32_t* __restrict__ pi_h,  // (B*N,128) half2
    const uint32_t* __restrict__ pj_h,  // (B*N,128) half2
    float* __restrict__ edge_out)     // (B,N,N)
{
    __shared__ __align__(16) uint32_t E_s[TI][TJ][12];     // dup'd h2v, 12 KiB
    __shared__ __align__(16) uint32_t We_es[EDGE_DIM][128]; // h2v, 4.5 KiB
    __shared__ __align__(16) uint32_t We2s[128];            // h2v, 0.5 KiB

    const int t    = threadIdx.x;
    const int lane = t & 63;
    const int wave = t >> 6;
    const int bi   = blockIdx.x;
    const int i0   = (bi >> 3) * TI;
    const int j0   = (bi & 7) * TJ;

    // ---- stage E tile as duplicated f16 pairs ----
#pragma unroll
    for (int ii = 0; ii < TI; ++ii) {
        const float* src = &E[((size_t)(i0 + ii) * NN + j0) * EDGE_DIM];
        for (int idx = t; idx < TJ * EDGE_DIM; idx += 512) {
            const int jl = idx / 9;
            const int d  = idx - jl * 9;
            const float e = src[idx];
            E_s[ii][jl][d] = h2u(pkrtz(e, e));
        }
    }
    // ---- stage We_e as h2v (9 x 128) ----
    for (int idx = t; idx < EDGE_DIM * 128; idx += 512) {
        const int d  = idx >> 7;
        const int hp = idx & 127;
        We_es[d][hp] = h2u(pkrtz(We_e[d * 256 + 2 * hp], We_e[d * 256 + 2 * hp + 1]));
    }
    // ---- stage We2 as h2v ----
    if (t < 128) We2s[t] = h2u(pkrtz(We2[2 * t], We2[2 * t + 1]));
    __syncthreads();

    const int r  = lane & 15;    // pair row
    const int c  = lane >> 4;    // k-chunk
    const int ii = r >> 2;       // i of pair
    const float be2v = be2[0];

#pragma unroll
    for (int g = 0; g < 2; ++g) {
        const int jl = wave * 8 + g * 4 + (r & 3);
        const int j  = j0 + jl;

        // E row for this lane's pair: 9 dup'd h2v
        const uint32_t* erow = &E_s[ii][jl][0];
        const uint4 ea = *(const uint4*)(erow);
        const uint4 eb = *(const uint4*)(erow + 4);
        const uint32_t ecw = erow[8];
        h2v ed[9];
        ed[0]=u2h(ea.x); ed[1]=u2h(ea.y); ed[2]=u2h(ea.z); ed[3]=u2h(ea.w);
        ed[4]=u2h(eb.x); ed[5]=u2h(eb.y); ed[6]=u2h(eb.z); ed[7]=u2h(eb.w);
        ed[8]=u2h(ecw);

        const uint32_t* weeP = &We_es[0][0] + 4 * c;   // + d*128 + 16*t8
        const uint32_t* we2P = We2s + 4 * c;           // + 16*t8
        const uint32_t* piP0 = pi_h + (size_t)(0 * NN + i0 + ii) * 128 + 4 * c;
        const uint32_t* piP1 = pi_h + (size_t)(1 * NN + i0 + ii) * 128 + 4 * c;
        const uint32_t* pjP0 = pj_h + (size_t)(0 * NN + j) * 128 + 4 * c;
        const uint32_t* pjP1 = pj_h + (size_t)(1 * NN + j) * 128 + 4 * c;

        f32x4 C0 = {be2v, be2v, be2v, be2v};
        f32x4 C1 = {be2v, be2v, be2v, be2v};

#pragma unroll
        for (int t8 = 0; t8 < 8; ++t8) {
            const int off = 16 * t8;

            // pe for this lane's 8 h
            h2v pe[4];
            {
                const uint4 w = *(const uint4*)(weeP + off);   // d = 0
                pe[0] = ed[0] * u2h(w.x); pe[1] = ed[0] * u2h(w.y);
                pe[2] = ed[0] * u2h(w.z); pe[3] = ed[0] * u2h(w.w);
            }
#pragma unroll
            for (int d = 1; d < EDGE_DIM; ++d) {
                const uint4 w = *(const uint4*)(weeP + d * 128 + off);
                pe[0] += ed[d] * u2h(w.x); pe[1] += ed[d] * u2h(w.y);
                pe[2] += ed[d] * u2h(w.z); pe[3] += ed[d] * u2h(w.w);
            }

            // B fragment: We2 slice (same for all cols)
            H8 bf;
            {
                const uint4 w = *(const uint4*)(we2P + off);
                bf.v[0] = u2h(w.x); bf.v[1] = u2h(w.y);
                bf.v[2] = u2h(w.z); bf.v[3] = u2h(w.w);
            }
            const f16x8 B = __builtin_bit_cast(f16x8, bf);

            // b = 0
            {
                const uint4 pi4 = *(const uint4*)(piP0 + off);
                const uint4 pj4 = *(const uint4*)(pjP0 + off);
                H8 a;
                a.v[0] = relu2(u2h(pi4.x) + u2h(pj4.x) + pe[0]);
                a.v[1] = relu2(u2h(pi4.y) + u2h(pj4.y) + pe[1]);
                a.v[2] = relu2(u2h(pi4.z) + u2h(pj4.z) + pe[2]);
                a.v[3] = relu2(u2h(pi4.w) + u2h(pj4.w) + pe[3]);
                C0 = __builtin_amdgcn_mfma_f32_16x16x32_f16(
                         __builtin_bit_cast(f16x8, a), B, C0, 0, 0, 0);
            }
            // b = 1
            {
                const uint4 pi4 = *(const uint4*)(piP1 + off);
                const uint4 pj4 = *(const uint4*)(pjP1 + off);
                H8 a;
                a.v[0] = relu2(u2h(pi4.x) + u2h(pj4.x) + pe[0]);
                a.v[1] = relu2(u2h(pi4.y) + u2h(pj4.y) + pe[1]);
                a.v[2] = relu2(u2h(pi4.z) + u2h(pj4.z) + pe[2]);
                a.v[3] = relu2(u2h(pi4.w) + u2h(pj4.w) + pe[3]);
                C1 = __builtin_amdgcn_mfma_f32_16x16x32_f16(
                         __builtin_bit_cast(f16x8, a), B, C1, 0, 0, 0);
            }
        }

        // Epilogue: lanes with r==0 hold rows 4c..4c+3 of col 0.
        if (r == 0) {
            const int i  = i0 + c;
            const int jb = j0 + wave * 8 + g * 4;
            const int4 m4 = *(const int4*)&mask[i * NN + jb];
            float4 o;
            o.x = sigmoidf_(C0.x) * (float)m4.x;
            o.y = sigmoidf_(C0.y) * (float)m4.y;
            o.z = sigmoidf_(C0.z) * (float)m4.z;
            o.w = sigmoidf_(C0.w) * (float)m4.w;
            *(float4*)&edge_out[((size_t)0 * NN + i) * NN + jb] = o;
            o.x = sigmoidf_(C1.x) * (float)m4.x;
            o.y = sigmoidf_(C1.y) * (float)m4.y;
            o.z = sigmoidf_(C1.z) * (float)m4.z;
            o.w = sigmoidf_(C1.w) * (float)m4.w;
            *(float4*)&edge_out[((size_t)1 * NN + i) * NN + jb] = o;
        }
    }
}

extern "C" void kernel_launch(void* const* d_in, const int* in_sizes, int n_in,
                              void* d_out, int out_size, void* d_ws, size_t ws_size,
                              hipStream_t stream) {
    const float* z    = (const float*)d_in[0];   // (B,N,128)
    const float* E    = (const float*)d_in[1];   // (N,N,9)
    const int*   mask = (const int*)  d_in[2];   // (N,N)
    const float* Wo1  = (const float*)d_in[3];
    const float* bo1  = (const float*)d_in[4];
    const float* Wo2  = (const float*)d_in[5];
    const float* bo2  = (const float*)d_in[6];
    const float* We_i = (const float*)d_in[7];
    const float* We_j = (const float*)d_in[8];
    const float* We_e = (const float*)d_in[9];
    const float* be1  = (const float*)d_in[10];
    const float* We2  = (const float*)d_in[11];
    const float* be2  = (const float*)d_in[12];

    float* out_organ = (float*)d_out;                 // (B,N) = 1024
    float* out_edge  = out_organ + BATCH * NN;        // (B,N,N)

    uint32_t* pi_h = (uint32_t*)d_ws;                        // (B*N,128) half2
    uint32_t* pj_h = pi_h + (size_t)BATCH * NN * (HIDDEN/2); // (B*N,128) half2

    hipLaunchKernelGGL(node_proj_kernel,
                       dim3((BATCH * NN) / 4), dim3(512), 0, stream,
                       z, Wo1, bo1, Wo2, bo2, We_i, We_j, be1,
                       out_organ, pi_h, pj_h);

    hipLaunchKernelGGL(edge_kernel,
                       dim3((NN / TI) * (NN / TJ)), dim3(512), 0, stream,
                       E, mask, We_e, We2, be2, pi_h, pj_h, out_edge);
}

// Round 6
// 55.872 us; speedup vs baseline: 1.2746x; 1.2746x over previous
//
#include <hip/hip_runtime.h>
#include <math.h>
#include <stdint.h>

#define D_MODEL 128
#define EDGE_DIM 9
#define HIDDEN 256
#define BATCH 2
#define NN 512

#define TI 4     // i-tile in kernel 2
#define TJ 32    // j-tile in kernel 2

typedef _Float16 h2v   __attribute__((ext_vector_type(2)));
typedef __fp16   fp16x2 __attribute__((ext_vector_type(2)));

__device__ __forceinline__ uint32_t h2u(h2v v) { return __builtin_bit_cast(uint32_t, v); }
__device__ __forceinline__ h2v u2h(uint32_t u) { return __builtin_bit_cast(h2v, u); }
__device__ __forceinline__ h2v pkrtz(float a, float b) {
    return __builtin_bit_cast(h2v, __builtin_amdgcn_cvt_pkrtz(a, b));
}
__device__ __forceinline__ h2v relu2(h2v v) {
    h2v z = {(_Float16)0.0f, (_Float16)0.0f};
    return __builtin_elementwise_max(v, z);
}
__device__ __forceinline__ float fdot2(h2v a, h2v b, float c) {
    return __builtin_amdgcn_fdot2(__builtin_bit_cast(fp16x2, a),
                                  __builtin_bit_cast(fp16x2, b), c, false);
}
__device__ __forceinline__ float sigmoidf_(float x) { return 1.f / (1.f + expf(-x)); }

// ---------------------------------------------------------------------------
// Kernel 1: pi = f16(z@We_i + be1), pj = f16(z@We_j), organ head f32.
// 256 blocks x 512 thr = 8 waves. Wave w: row w&3, d-half w>>2 (d-split for
// 2 waves/SIMD + halved dependency chain). Lane owns 4 h (float4 weight
// loads). dh=1 waves park partials in LDS; dh=0 waves combine, do the organ
// shfl-reduce, and emit packed-f16 pi/pj.
// ---------------------------------------------------------------------------
__global__ __launch_bounds__(512) void node_proj_kernel(
    const float* __restrict__ z,      // (B*N, 128)
    const float* __restrict__ Wo1,    // (128,256)
    const float* __restrict__ bo1,    // (256)
    const float* __restrict__ Wo2,    // (256,1)
    const float* __restrict__ bo2,    // (1)
    const float* __restrict__ We_i,   // (128,256)
    const float* __restrict__ We_j,   // (128,256)
    const float* __restrict__ be1,    // (256)
    float* __restrict__ organ_out,    // (B*N)
    uint32_t* __restrict__ pi_h,      // (B*N,128) half2, includes +be1
    uint32_t* __restrict__ pj_h)      // (B*N,128) half2
{
    __shared__ float z_s[4][D_MODEL];
    __shared__ float4 partO[4][64], partI[4][64], partJ[4][64];  // 12 KiB

    const int t  = threadIdx.x;
    const int r0 = blockIdx.x * 4;

    z_s[t >> 7][t & 127] = z[r0 * D_MODEL + t];
    __syncthreads();

    const int wave = t >> 6, lane = t & 63;
    const int rl = wave & 3;          // row within tile
    const int dh = wave >> 2;         // d-half

    float4 accO, accI, accJ;
    accJ.x = accJ.y = accJ.z = accJ.w = 0.f;
    if (dh == 0) {
        accO = ((const float4*)bo1)[lane];
        accI = ((const float4*)be1)[lane];
    } else {
        accO.x = accO.y = accO.z = accO.w = 0.f;
        accI.x = accI.y = accI.z = accI.w = 0.f;
    }

    const float* zr = z_s[rl];
    const int dbase = dh * 64;

#pragma unroll 8
    for (int d0 = 0; d0 < 64; ++d0) {
        const int d = dbase + d0;
        const float4 w1 = ((const float4*)Wo1 )[d * 64 + lane];
        const float4 wi = ((const float4*)We_i)[d * 64 + lane];
        const float4 wj = ((const float4*)We_j)[d * 64 + lane];
        const float zv = zr[d];
        accO.x = fmaf(zv, w1.x, accO.x); accO.y = fmaf(zv, w1.y, accO.y);
        accO.z = fmaf(zv, w1.z, accO.z); accO.w = fmaf(zv, w1.w, accO.w);
        accI.x = fmaf(zv, wi.x, accI.x); accI.y = fmaf(zv, wi.y, accI.y);
        accI.z = fmaf(zv, wi.z, accI.z); accI.w = fmaf(zv, wi.w, accI.w);
        accJ.x = fmaf(zv, wj.x, accJ.x); accJ.y = fmaf(zv, wj.y, accJ.y);
        accJ.z = fmaf(zv, wj.z, accJ.z); accJ.w = fmaf(zv, wj.w, accJ.w);
    }

    if (dh == 1) {
        partO[rl][lane] = accO;
        partI[rl][lane] = accI;
        partJ[rl][lane] = accJ;
    }
    __syncthreads();

    if (dh == 0) {
        const float4 pO = partO[rl][lane];
        const float4 pI = partI[rl][lane];
        const float4 pJ = partJ[rl][lane];
        accO.x += pO.x; accO.y += pO.y; accO.z += pO.z; accO.w += pO.w;
        accI.x += pI.x; accI.y += pI.y; accI.z += pI.z; accI.w += pI.w;
        accJ.x += pJ.x; accJ.y += pJ.y; accJ.z += pJ.z; accJ.w += pJ.w;

        // organ head (f32): v = relu(accO) . Wo2, 64-lane butterfly
        const float4 wo2 = ((const float4*)Wo2)[lane];
        float v = fmaf(fmaxf(accO.x, 0.f), wo2.x,
                  fmaf(fmaxf(accO.y, 0.f), wo2.y,
                  fmaf(fmaxf(accO.z, 0.f), wo2.z,
                       fmaxf(accO.w, 0.f) * wo2.w)));
#pragma unroll
        for (int s = 1; s <= 32; s <<= 1) v += __shfl_xor(v, s, 64);
        if (lane == 0) organ_out[r0 + rl] = sigmoidf_(v + bo2[0]);

        const size_t row = (size_t)(r0 + rl);
        uint2 upi, upj;
        upi.x = h2u(pkrtz(accI.x, accI.y));
        upi.y = h2u(pkrtz(accI.z, accI.w));
        upj.x = h2u(pkrtz(accJ.x, accJ.y));
        upj.y = h2u(pkrtz(accJ.z, accJ.w));
        *(uint2*)&pi_h[row * 128 + 2 * lane] = upi;
        *(uint2*)&pj_h[row * 128 + 2 * lane] = upj;
    }
}

// ---------------------------------------------------------------------------
// Kernel 2: fused edge head (round-4 data layout + batched transpose-reduce).
// grid 2048 x 256 thr (4 waves, 8 blocks/CU). Wave w: jl = w*8+q. Lane owns
// h = 4*lane (2 half2); wee/w2/pi register-resident; E in LDS (dup'd h2v);
// pj prefetched one q ahead. Per q: 4 ii pairs x 2 b = 8 partial dots in
// vals[8]; ONE batched reduce (3 select+xchg steps xor 1/2/4, then butterfly
// xor 8/16/32) -> lane L<8 holds output (b=L&1, ii=L>>1). Amortizes the
// serial shfl chain 4x vs per-pair butterflies.
// ---------------------------------------------------------------------------
__global__ __launch_bounds__(256, 8) void edge_kernel(
    const float* __restrict__ E,      // (N,N,9)
    const int*   __restrict__ mask,   // (N,N)
    const float* __restrict__ We_e,   // (9,256)
    const float* __restrict__ We2,    // (256,1)
    const float* __restrict__ be2,    // (1)
    const uint32_t* __restrict__ pi_h,  // (B*N,128) half2
    const uint32_t* __restrict__ pj_h,  // (B*N,128) half2
    float* __restrict__ edge_out)     // (B,N,N)
{
    __shared__ __align__(16) uint32_t E_s[TI][TJ][12];  // dup'd h2v, 6 KiB
    __shared__ float sums_s[BATCH][TI][33];             // padded, ~1 KiB

    const int t    = threadIdx.x;
    const int lane = t & 63;
    const int wave = t >> 6;           // 0..3
    const int bi   = blockIdx.x;
    const int i0   = (bi >> 4) * TI;   // 128 i-blocks
    const int j0   = (bi & 15) * TJ;   // 16 j-blocks

    // ---- stage E tile as duplicated f16 pairs ----
#pragma unroll
    for (int ii = 0; ii < TI; ++ii) {
        const float* src = &E[((size_t)(i0 + ii) * NN + j0) * EDGE_DIM];
        for (int idx = t; idx < TJ * EDGE_DIM; idx += 256) {
            const int jl = idx / 9;
            const int d  = idx - jl * 9;
            const float e = src[idx];
            E_s[ii][jl][d] = h2u(pkrtz(e, e));
        }
    }

    // ---- register-resident weights: h = 4*lane + {0,1}|{2,3} ----
    h2v wee[EDGE_DIM][2];
    const float4* We_e4 = (const float4*)We_e;
#pragma unroll
    for (int d = 0; d < EDGE_DIM; ++d) {
        const float4 w = We_e4[d * 64 + lane];
        wee[d][0] = pkrtz(w.x, w.y);
        wee[d][1] = pkrtz(w.z, w.w);
    }
    h2v w2[2];
    {
        const float4 w = ((const float4*)We2)[lane];
        w2[0] = pkrtz(w.x, w.y);
        w2[1] = pkrtz(w.z, w.w);
    }

    h2v pir[BATCH][TI][2];
#pragma unroll
    for (int b = 0; b < BATCH; ++b)
#pragma unroll
        for (int ii = 0; ii < TI; ++ii) {
            const uint2 u = ((const uint2*)&pi_h[(size_t)(b * NN + i0 + ii) * 128])[lane];
            pir[b][ii][0] = u2h(u.x);
            pir[b][ii][1] = u2h(u.y);
        }

    __syncthreads();

    // ---- prefetch pj for q=0 ----
    uint2 pjp[BATCH];
    {
        const int j = j0 + wave * 8;
        pjp[0] = ((const uint2*)&pj_h[(size_t)(0 * NN + j) * 128])[lane];
        pjp[1] = ((const uint2*)&pj_h[(size_t)(1 * NN + j) * 128])[lane];
    }

#pragma unroll
    for (int q = 0; q < 8; ++q) {
        const int jl = wave * 8 + q;

        h2v pjr[BATCH][2];
        pjr[0][0] = u2h(pjp[0].x); pjr[0][1] = u2h(pjp[0].y);
        pjr[1][0] = u2h(pjp[1].x); pjr[1][1] = u2h(pjp[1].y);

        if (q < 7) {  // prefetch next q
            const int j = j0 + jl + 1;
            pjp[0] = ((const uint2*)&pj_h[(size_t)(0 * NN + j) * 128])[lane];
            pjp[1] = ((const uint2*)&pj_h[(size_t)(1 * NN + j) * 128])[lane];
        }

        float vals[8];
#pragma unroll
        for (int ii = 0; ii < TI; ++ii) {
            const uint32_t* erow = &E_s[ii][jl][0];
            const uint4 ua = *(const uint4*)(erow);
            const uint4 ub = *(const uint4*)(erow + 4);
            const uint32_t uc = erow[8];

            h2v pe0, pe1;
            {
                const h2v e0 = u2h(ua.x), e1 = u2h(ua.y), e2 = u2h(ua.z), e3 = u2h(ua.w);
                const h2v e4 = u2h(ub.x), e5 = u2h(ub.y), e6 = u2h(ub.z), e7 = u2h(ub.w);
                const h2v e8 = u2h(uc);
                pe0 = e0 * wee[0][0];            pe1 = e0 * wee[0][1];
                pe0 = pe0 + e1 * wee[1][0];      pe1 = pe1 + e1 * wee[1][1];
                pe0 = pe0 + e2 * wee[2][0];      pe1 = pe1 + e2 * wee[2][1];
                pe0 = pe0 + e3 * wee[3][0];      pe1 = pe1 + e3 * wee[3][1];
                pe0 = pe0 + e4 * wee[4][0];      pe1 = pe1 + e4 * wee[4][1];
                pe0 = pe0 + e5 * wee[5][0];      pe1 = pe1 + e5 * wee[5][1];
                pe0 = pe0 + e6 * wee[6][0];      pe1 = pe1 + e6 * wee[6][1];
                pe0 = pe0 + e7 * wee[7][0];      pe1 = pe1 + e7 * wee[7][1];
                pe0 = pe0 + e8 * wee[8][0];      pe1 = pe1 + e8 * wee[8][1];
            }

#pragma unroll
            for (int b = 0; b < BATCH; ++b) {
                h2v v0 = relu2(pir[b][ii][0] + pjr[b][0] + pe0);
                h2v v1 = relu2(pir[b][ii][1] + pjr[b][1] + pe1);
                vals[2 * ii + b] = fdot2(v1, w2[1], fdot2(v0, w2[0], 0.f));
            }
        }

        // ---- batched transpose-reduce: 8 values over 64 lanes ----
        float a0, a1, a2, a3;
        {
            const bool b0 = lane & 1;
            float k0 = b0 ? vals[1] : vals[0], s0 = b0 ? vals[0] : vals[1];
            float k1 = b0 ? vals[3] : vals[2], s1 = b0 ? vals[2] : vals[3];
            float k2 = b0 ? vals[5] : vals[4], s2 = b0 ? vals[4] : vals[5];
            float k3 = b0 ? vals[7] : vals[6], s3 = b0 ? vals[6] : vals[7];
            a0 = k0 + __shfl_xor(s0, 1, 64);
            a1 = k1 + __shfl_xor(s1, 1, 64);
            a2 = k2 + __shfl_xor(s2, 1, 64);
            a3 = k3 + __shfl_xor(s3, 1, 64);
        }
        {
            const bool b1 = (lane >> 1) & 1;
            float k0 = b1 ? a1 : a0, s0 = b1 ? a0 : a1;
            float k1 = b1 ? a3 : a2, s1 = b1 ? a2 : a3;
            a0 = k0 + __shfl_xor(s0, 2, 64);
            a1 = k1 + __shfl_xor(s1, 2, 64);
        }
        {
            const bool b2 = (lane >> 2) & 1;
            float k = b2 ? a1 : a0, s = b2 ? a0 : a1;
            a0 = k + __shfl_xor(s, 4, 64);
        }
        a0 += __shfl_xor(a0, 8, 64);
        a0 += __shfl_xor(a0, 16, 64);
        a0 += __shfl_xor(a0, 32, 64);

        // lane L<8 holds output idx L: b = L&1, ii = L>>1
        if (lane < 8) sums_s[lane & 1][lane >> 1][jl] = a0;
    }
    __syncthreads();

    // Epilogue: one output per thread (256 = BATCH*TI*TJ).
    {
        const int b   = t >> 7;
        const int rem = t & 127;
        const int ii  = rem >> 5;
        const int jl  = rem & 31;
        const int i = i0 + ii, j = j0 + jl;
        const float s = sums_s[b][ii][jl] + be2[0];
        float p = sigmoidf_(s) * (float)mask[i * NN + j];
        edge_out[((size_t)b * NN + i) * NN + j] = p;
    }
}

extern "C" void kernel_launch(void* const* d_in, const int* in_sizes, int n_in,
                              void* d_out, int out_size, void* d_ws, size_t ws_size,
                              hipStream_t stream) {
    const float* z    = (const float*)d_in[0];   // (B,N,128)
    const float* E    = (const float*)d_in[1];   // (N,N,9)
    const int*   mask = (const int*)  d_in[2];   // (N,N)
    const float* Wo1  = (const float*)d_in[3];
    const float* bo1  = (const float*)d_in[4];
    const float* Wo2  = (const float*)d_in[5];
    const float* bo2  = (const float*)d_in[6];
    const float* We_i = (const float*)d_in[7];
    const float* We_j = (const float*)d_in[8];
    const float* We_e = (const float*)d_in[9];
    const float* be1  = (const float*)d_in[10];
    const float* We2  = (const float*)d_in[11];
    const float* be2  = (const float*)d_in[12];

    float* out_organ = (float*)d_out;                 // (B,N) = 1024
    float* out_edge  = out_organ + BATCH * NN;        // (B,N,N)

    uint32_t* pi_h = (uint32_t*)d_ws;                        // (B*N,128) half2
    uint32_t* pj_h = pi_h + (size_t)BATCH * NN * (HIDDEN/2); // (B*N,128) half2

    hipLaunchKernelGGL(node_proj_kernel,
                       dim3((BATCH * NN) / 4), dim3(512), 0, stream,
                       z, Wo1, bo1, Wo2, bo2, We_i, We_j, be1,
                       out_organ, pi_h, pj_h);

    hipLaunchKernelGGL(edge_kernel,
                       dim3((NN / TI) * (NN / TJ)), dim3(256), 0, stream,
                       E, mask, We_e, We2, be2, pi_h, pj_h, out_edge);
}

// Round 7
// 41.683 us; speedup vs baseline: 1.7086x; 1.3404x over previous
//
#include <hip/hip_runtime.h>
#include <math.h>
#include <stdint.h>

#define D_MODEL 128
#define EDGE_DIM 9
#define HIDDEN 256
#define BATCH 2
#define NN 512

#define TI 4     // i-tile in kernel 2
#define TJ 32    // j-tile in kernel 2

typedef _Float16 h2v    __attribute__((ext_vector_type(2)));
typedef __fp16   fp16x2 __attribute__((ext_vector_type(2)));
typedef _Float16 f16x8  __attribute__((ext_vector_type(8)));
typedef float    f32x4  __attribute__((ext_vector_type(4)));

struct H8 { h2v v[4]; };   // 16B = one MFMA A/B fragment

__device__ __forceinline__ uint32_t h2u(h2v v) { return __builtin_bit_cast(uint32_t, v); }
__device__ __forceinline__ h2v u2h(uint32_t u) { return __builtin_bit_cast(h2v, u); }
__device__ __forceinline__ h2v pkrtz(float a, float b) {
    return __builtin_bit_cast(h2v, __builtin_amdgcn_cvt_pkrtz(a, b));
}
__device__ __forceinline__ h2v relu2(h2v v) {
    h2v z = {(_Float16)0.0f, (_Float16)0.0f};
    return __builtin_elementwise_max(v, z);
}
__device__ __forceinline__ float fdot2(h2v a, h2v b, float c) {
    return __builtin_amdgcn_fdot2(__builtin_bit_cast(fp16x2, a),
                                  __builtin_bit_cast(fp16x2, b), c, false);
}
__device__ __forceinline__ float sigmoidf_(float x) { return 1.f / (1.f + expf(-x)); }

// ---------------------------------------------------------------------------
// Kernel 1 (MFMA): C = z @ W for one of {Wo1, We_i, We_j} per block.y.
// Grid (32, 3), 512 thr = 8 waves. Block = 32 rows x 256 cols, K = 128.
// W staged once to LDS as f16 d-pairs, TRANSPOSED [h][d2], pitch 68 (16B
// aligned rows), XOR-swizzled d2 ^= (h&7)<<3 for bank spread. A-frags loaded
// straight from global z (f32 -> pkrtz). Wave w: row-tile rt=w&1, col-group
// cg=w>>1 (4 col-tiles of 16). 16 MFMAs/wave (mfma_f32_16x16x32_f16,
// layouts HW-validated in round 5).
// Epilogue m=0: organ head in-block (relu(C+bo1)*Wo2, 16-lane reduce, LDS
// combine over cg, sigmoid). m=1/2: pi/pj packed f16 via neighbor-lane pair.
// ---------------------------------------------------------------------------
__global__ __launch_bounds__(512) void node_mfma_kernel(
    const float* __restrict__ z,      // (B*N, 128)
    const float* __restrict__ Wo1,    // (128,256)
    const float* __restrict__ bo1,    // (256)
    const float* __restrict__ Wo2,    // (256,1)
    const float* __restrict__ bo2,    // (1)
    const float* __restrict__ We_i,   // (128,256)
    const float* __restrict__ We_j,   // (128,256)
    const float* __restrict__ be1,    // (256)
    float* __restrict__ organ_out,    // (B*N)
    uint32_t* __restrict__ pi_h,      // (B*N,128) half2, includes +be1
    uint32_t* __restrict__ pj_h)      // (B*N,128) half2
{
    __shared__ uint32_t Wlds[256][68];     // ~69.6 KiB, f16-pair, [h][d2^swz]
    __shared__ float org_part[32][4];

    const int t    = threadIdx.x;
    const int lane = t & 63;
    const int wave = t >> 6;
    const int rb   = blockIdx.x;           // row-block: rows 32*rb..32*rb+31
    const int m    = blockIdx.y;           // 0 = Wo1/organ, 1 = We_i/pi, 2 = We_j/pj

    const float* __restrict__ W = (m == 0) ? Wo1 : (m == 1) ? We_i : We_j;

    // ---- stage W -> LDS f16, transposed, swizzled ----
    for (int idx = t; idx < 64 * 256; idx += 512) {
        const int d2 = idx >> 8;           // 0..63 (d-pair)
        const int h  = idx & 255;          // coalesced over h
        const float wlo = W[(2 * d2) * 256 + h];
        const float whi = W[(2 * d2 + 1) * 256 + h];
        Wlds[h][d2 ^ ((h & 7) << 3)] = h2u(pkrtz(wlo, whi));
    }

    // ---- A-frags straight from global (while staging lands) ----
    const int rt = wave & 1;               // row-tile
    const int cg = wave >> 1;              // col-group (4 tiles of 16)
    const int kg = lane >> 4;              // k-subgroup
    const int row = rb * 32 + rt * 16 + (lane & 15);

    f16x8 A[4];
#pragma unroll
    for (int kt = 0; kt < 4; ++kt) {
        const float4 za = *(const float4*)&z[(size_t)row * 128 + kt * 32 + kg * 8];
        const float4 zb = *(const float4*)&z[(size_t)row * 128 + kt * 32 + kg * 8 + 4];
        H8 a;
        a.v[0] = pkrtz(za.x, za.y); a.v[1] = pkrtz(za.z, za.w);
        a.v[2] = pkrtz(zb.x, zb.y); a.v[3] = pkrtz(zb.z, zb.w);
        A[kt] = __builtin_bit_cast(f16x8, a);
    }

    __syncthreads();

    // ---- MFMA main: 4 col-tiles x 4 k-tiles ----
    f32x4 C[4];
#pragma unroll
    for (int ct = 0; ct < 4; ++ct) {
        const int col = (cg * 4 + ct) * 16 + (lane & 15);
        C[ct] = (f32x4){0.f, 0.f, 0.f, 0.f};
#pragma unroll
        for (int kt = 0; kt < 4; ++kt) {
            const int d2b = (kt * 16 + kg * 4) ^ ((col & 7) << 3);
            const uint4 w = *(const uint4*)&Wlds[col][d2b];
            H8 b;
            b.v[0] = u2h(w.x); b.v[1] = u2h(w.y);
            b.v[2] = u2h(w.z); b.v[3] = u2h(w.w);
            C[ct] = __builtin_amdgcn_mfma_f32_16x16x32_f16(
                        A[kt], __builtin_bit_cast(f16x8, b), C[ct], 0, 0, 0);
        }
    }

    // ---- epilogues ----
    if (m == 0) {
        // organ: s[r] = sum_cols relu(C+bo1)*Wo2 over this wave's 64 cols
        float s0 = 0.f, s1 = 0.f, s2 = 0.f, s3 = 0.f;
#pragma unroll
        for (int ct = 0; ct < 4; ++ct) {
            const int col = (cg * 4 + ct) * 16 + (lane & 15);
            const float b1 = bo1[col];
            const float w2 = Wo2[col];
            s0 = fmaf(fmaxf(C[ct].x + b1, 0.f), w2, s0);
            s1 = fmaf(fmaxf(C[ct].y + b1, 0.f), w2, s1);
            s2 = fmaf(fmaxf(C[ct].z + b1, 0.f), w2, s2);
            s3 = fmaf(fmaxf(C[ct].w + b1, 0.f), w2, s3);
        }
#pragma unroll
        for (int off = 1; off <= 8; off <<= 1) {
            s0 += __shfl_xor(s0, off, 64);
            s1 += __shfl_xor(s1, off, 64);
            s2 += __shfl_xor(s2, off, 64);
            s3 += __shfl_xor(s3, off, 64);
        }
        if ((lane & 15) == 0) {
            const int rbase = rt * 16 + kg * 4;
            org_part[rbase + 0][cg] = s0;
            org_part[rbase + 1][cg] = s1;
            org_part[rbase + 2][cg] = s2;
            org_part[rbase + 3][cg] = s3;
        }
        __syncthreads();
        if (t < 32) {
            const float s = org_part[t][0] + org_part[t][1]
                          + org_part[t][2] + org_part[t][3] + bo2[0];
            organ_out[rb * 32 + t] = sigmoidf_(s);
        }
    } else {
        uint32_t* __restrict__ dst = (m == 1) ? pi_h : pj_h;
        const bool addb = (m == 1);
#pragma unroll
        for (int ct = 0; ct < 4; ++ct) {
            const int col = (cg * 4 + ct) * 16 + (lane & 15);
            const float bv = addb ? be1[col] : 0.f;
            float v0 = C[ct].x + bv, v1 = C[ct].y + bv;
            float v2 = C[ct].z + bv, v3 = C[ct].w + bv;
            const float p0 = __shfl_xor(v0, 1, 64);
            const float p1 = __shfl_xor(v1, 1, 64);
            const float p2 = __shfl_xor(v2, 1, 64);
            const float p3 = __shfl_xor(v3, 1, 64);
            if (!(lane & 1)) {                 // even col: pack (col, col+1)
                const int hp = col >> 1;
                const size_t gr = (size_t)(rb * 32 + rt * 16 + kg * 4);
                dst[(gr + 0) * 128 + hp] = h2u(pkrtz(v0, p0));
                dst[(gr + 1) * 128 + hp] = h2u(pkrtz(v1, p1));
                dst[(gr + 2) * 128 + hp] = h2u(pkrtz(v2, p2));
                dst[(gr + 3) * 128 + hp] = h2u(pkrtz(v3, p3));
            }
        }
    }
}

// ---------------------------------------------------------------------------
// Kernel 2: fused edge head (unchanged from round 6).
// grid 2048 x 256 thr (4 waves, 8 blocks/CU). Wave w: jl = w*8+q. Lane owns
// h = 4*lane (2 half2); wee/w2/pi register-resident; E in LDS (dup'd h2v);
// pj prefetched one q ahead. Per q: 8 partial dots -> ONE batched
// transpose-reduce (xor 1/2/4 select+xchg, then butterfly 8/16/32).
// ---------------------------------------------------------------------------
__global__ __launch_bounds__(256, 8) void edge_kernel(
    const float* __restrict__ E,      // (N,N,9)
    const int*   __restrict__ mask,   // (N,N)
    const float* __restrict__ We_e,   // (9,256)
    const float* __restrict__ We2,    // (256,1)
    const float* __restrict__ be2,    // (1)
    const uint32_t* __restrict__ pi_h,  // (B*N,128) half2
    const uint32_t* __restrict__ pj_h,  // (B*N,128) half2
    float* __restrict__ edge_out)     // (B,N,N)
{
    __shared__ __align__(16) uint32_t E_s[TI][TJ][12];  // dup'd h2v, 6 KiB
    __shared__ float sums_s[BATCH][TI][33];             // padded, ~1 KiB

    const int t    = threadIdx.x;
    const int lane = t & 63;
    const int wave = t >> 6;           // 0..3
    const int bi   = blockIdx.x;
    const int i0   = (bi >> 4) * TI;   // 128 i-blocks
    const int j0   = (bi & 15) * TJ;   // 16 j-blocks

#pragma unroll
    for (int ii = 0; ii < TI; ++ii) {
        const float* src = &E[((size_t)(i0 + ii) * NN + j0) * EDGE_DIM];
        for (int idx = t; idx < TJ * EDGE_DIM; idx += 256) {
            const int jl = idx / 9;
            const int d  = idx - jl * 9;
            const float e = src[idx];
            E_s[ii][jl][d] = h2u(pkrtz(e, e));
        }
    }

    h2v wee[EDGE_DIM][2];
    const float4* We_e4 = (const float4*)We_e;
#pragma unroll
    for (int d = 0; d < EDGE_DIM; ++d) {
        const float4 w = We_e4[d * 64 + lane];
        wee[d][0] = pkrtz(w.x, w.y);
        wee[d][1] = pkrtz(w.z, w.w);
    }
    h2v w2[2];
    {
        const float4 w = ((const float4*)We2)[lane];
        w2[0] = pkrtz(w.x, w.y);
        w2[1] = pkrtz(w.z, w.w);
    }

    h2v pir[BATCH][TI][2];
#pragma unroll
    for (int b = 0; b < BATCH; ++b)
#pragma unroll
        for (int ii = 0; ii < TI; ++ii) {
            const uint2 u = ((const uint2*)&pi_h[(size_t)(b * NN + i0 + ii) * 128])[lane];
            pir[b][ii][0] = u2h(u.x);
            pir[b][ii][1] = u2h(u.y);
        }

    __syncthreads();

    uint2 pjp[BATCH];
    {
        const int j = j0 + wave * 8;
        pjp[0] = ((const uint2*)&pj_h[(size_t)(0 * NN + j) * 128])[lane];
        pjp[1] = ((const uint2*)&pj_h[(size_t)(1 * NN + j) * 128])[lane];
    }

#pragma unroll
    for (int q = 0; q < 8; ++q) {
        const int jl = wave * 8 + q;

        h2v pjr[BATCH][2];
        pjr[0][0] = u2h(pjp[0].x); pjr[0][1] = u2h(pjp[0].y);
        pjr[1][0] = u2h(pjp[1].x); pjr[1][1] = u2h(pjp[1].y);

        if (q < 7) {
            const int j = j0 + jl + 1;
            pjp[0] = ((const uint2*)&pj_h[(size_t)(0 * NN + j) * 128])[lane];
            pjp[1] = ((const uint2*)&pj_h[(size_t)(1 * NN + j) * 128])[lane];
        }

        float vals[8];
#pragma unroll
        for (int ii = 0; ii < TI; ++ii) {
            const uint32_t* erow = &E_s[ii][jl][0];
            const uint4 ua = *(const uint4*)(erow);
            const uint4 ub = *(const uint4*)(erow + 4);
            const uint32_t uc = erow[8];

            h2v pe0, pe1;
            {
                const h2v e0 = u2h(ua.x), e1 = u2h(ua.y), e2 = u2h(ua.z), e3 = u2h(ua.w);
                const h2v e4 = u2h(ub.x), e5 = u2h(ub.y), e6 = u2h(ub.z), e7 = u2h(ub.w);
                const h2v e8 = u2h(uc);
                pe0 = e0 * wee[0][0];            pe1 = e0 * wee[0][1];
                pe0 = pe0 + e1 * wee[1][0];      pe1 = pe1 + e1 * wee[1][1];
                pe0 = pe0 + e2 * wee[2][0];      pe1 = pe1 + e2 * wee[2][1];
                pe0 = pe0 + e3 * wee[3][0];      pe1 = pe1 + e3 * wee[3][1];
                pe0 = pe0 + e4 * wee[4][0];      pe1 = pe1 + e4 * wee[4][1];
                pe0 = pe0 + e5 * wee[5][0];      pe1 = pe1 + e5 * wee[5][1];
                pe0 = pe0 + e6 * wee[6][0];      pe1 = pe1 + e6 * wee[6][1];
                pe0 = pe0 + e7 * wee[7][0];      pe1 = pe1 + e7 * wee[7][1];
                pe0 = pe0 + e8 * wee[8][0];      pe1 = pe1 + e8 * wee[8][1];
            }

#pragma unroll
            for (int b = 0; b < BATCH; ++b) {
                h2v v0 = relu2(pir[b][ii][0] + pjr[b][0] + pe0);
                h2v v1 = relu2(pir[b][ii][1] + pjr[b][1] + pe1);
                vals[2 * ii + b] = fdot2(v1, w2[1], fdot2(v0, w2[0], 0.f));
            }
        }

        float a0, a1, a2, a3;
        {
            const bool b0 = lane & 1;
            float k0 = b0 ? vals[1] : vals[0], s0 = b0 ? vals[0] : vals[1];
            float k1 = b0 ? vals[3] : vals[2], s1 = b0 ? vals[2] : vals[3];
            float k2 = b0 ? vals[5] : vals[4], s2 = b0 ? vals[4] : vals[5];
            float k3 = b0 ? vals[7] : vals[6], s3 = b0 ? vals[6] : vals[7];
            a0 = k0 + __shfl_xor(s0, 1, 64);
            a1 = k1 + __shfl_xor(s1, 1, 64);
            a2 = k2 + __shfl_xor(s2, 1, 64);
            a3 = k3 + __shfl_xor(s3, 1, 64);
        }
        {
            const bool b1 = (lane >> 1) & 1;
            float k0 = b1 ? a1 : a0, s0 = b1 ? a0 : a1;
            float k1 = b1 ? a3 : a2, s1 = b1 ? a2 : a3;
            a0 = k0 + __shfl_xor(s0, 2, 64);
            a1 = k1 + __shfl_xor(s1, 2, 64);
        }
        {
            const bool b2 = (lane >> 2) & 1;
            float k = b2 ? a1 : a0, s = b2 ? a0 : a1;
            a0 = k + __shfl_xor(s, 4, 64);
        }
        a0 += __shfl_xor(a0, 8, 64);
        a0 += __shfl_xor(a0, 16, 64);
        a0 += __shfl_xor(a0, 32, 64);

        if (lane < 8) sums_s[lane & 1][lane >> 1][jl] = a0;
    }
    __syncthreads();

    {
        const int b   = t >> 7;
        const int rem = t & 127;
        const int ii  = rem >> 5;
        const int jl  = rem & 31;
        const int i = i0 + ii, j = j0 + jl;
        const float s = sums_s[b][ii][jl] + be2[0];
        float p = sigmoidf_(s) * (float)mask[i * NN + j];
        edge_out[((size_t)b * NN + i) * NN + j] = p;
    }
}

extern "C" void kernel_launch(void* const* d_in, const int* in_sizes, int n_in,
                              void* d_out, int out_size, void* d_ws, size_t ws_size,
                              hipStream_t stream) {
    const float* z    = (const float*)d_in[0];   // (B,N,128)
    const float* E    = (const float*)d_in[1];   // (N,N,9)
    const int*   mask = (const int*)  d_in[2];   // (N,N)
    const float* Wo1  = (const float*)d_in[3];
    const float* bo1  = (const float*)d_in[4];
    const float* Wo2  = (const float*)d_in[5];
    const float* bo2  = (const float*)d_in[6];
    const float* We_i = (const float*)d_in[7];
    const float* We_j = (const float*)d_in[8];
    const float* We_e = (const float*)d_in[9];
    const float* be1  = (const float*)d_in[10];
    const float* We2  = (const float*)d_in[11];
    const float* be2  = (const float*)d_in[12];

    float* out_organ = (float*)d_out;                 // (B,N) = 1024
    float* out_edge  = out_organ + BATCH * NN;        // (B,N,N)

    uint32_t* pi_h = (uint32_t*)d_ws;                        // (B*N,128) half2
    uint32_t* pj_h = pi_h + (size_t)BATCH * NN * (HIDDEN/2); // (B*N,128) half2

    hipLaunchKernelGGL(node_mfma_kernel,
                       dim3(32, 3), dim3(512), 0, stream,
                       z, Wo1, bo1, Wo2, bo2, We_i, We_j, be1,
                       out_organ, pi_h, pj_h);

    hipLaunchKernelGGL(edge_kernel,
                       dim3((NN / TI) * (NN / TJ)), dim3(256), 0, stream,
                       E, mask, We_e, We2, be2, pi_h, pj_h, out_edge);
}